// Round 5
// baseline (97.036 us; speedup 1.0000x reference)
//
#include <hip/hip_runtime.h>

#define DIM   1024
#define SEQ_  2048
#define NBAT  4
// DIAGNOSTIC ROUND: identical idempotent kernel launched 8x in the captured
// graph. Dispatch 1 is HBM-cold; 2-8 are L3-warm (working set ~70MB < 256MB
// L3). dur_us decomposes into t_cold + 7*t_warm + gaps, separating the
// cold-HBM premium from fixed overhead. Output identical to single launch.

__global__ __launch_bounds__(256) void verse_embed_ln_kernel(
    const int*   __restrict__ token_ids,    // [B,S]
    const int*   __restrict__ verse_pos,    // [B,S]
    const int*   __restrict__ book_types,   // [B,S]
    const float* __restrict__ emb_table,    // [VOCAB,D]
    const float* __restrict__ book_table,   // [4,D]
    const float* __restrict__ gamma,        // [D]
    const float* __restrict__ beta,         // [D]
    float*       __restrict__ out)          // [B,S,D]
{
    __shared__ float4 bookLDS[1024];        // [type][chunk][lane] = 16 KB

    const int t    = threadIdx.x;
    const int wid  = t >> 6;
    const int lane = t & 63;
    const int base = ((blockIdx.x << 2) + wid) << 1;   // first of 2 rows

    const float4* __restrict__ bt4 = reinterpret_cast<const float4*>(book_table);
    #pragma unroll
    for (int k = 0; k < 4; ++k)
        bookLDS[k * 256 + t] = bt4[k * 256 + t];

    const int tok0 = token_ids[base],   tok1 = token_ids[base + 1];
    const int bt0  = book_types[base],  bt1  = book_types[base + 1];
    const int v0   = verse_pos[base],   v1   = verse_pos[base + 1];
    const int s0   = base & (SEQ_ - 1);
    const int vp0  = (s0 == 0) ? -1 : verse_pos[base - 1];
    const float w0 = (v0 != 0 && v0 != vp0) ? 1.2f : 1.0f;
    const float w1 = (v1 != 0 && v1 != v0)  ? 1.2f : 1.0f;

    const float4* __restrict__ er0 = reinterpret_cast<const float4*>(emb_table) + (size_t)tok0 * 256;
    const float4* __restrict__ er1 = reinterpret_cast<const float4*>(emb_table) + (size_t)tok1 * 256;
    float4 e[2][4];
    #pragma unroll
    for (int c = 0; c < 4; ++c) e[0][c] = er0[c * 64 + lane];
    #pragma unroll
    for (int c = 0; c < 4; ++c) e[1][c] = er1[c * 64 + lane];

    const float4* __restrict__ g4 = reinterpret_cast<const float4*>(gamma);
    const float4* __restrict__ b4 = reinterpret_cast<const float4*>(beta);
    float4 g[4], b[4];
    #pragma unroll
    for (int c = 0; c < 4; ++c) { g[c] = g4[c * 64 + lane]; b[c] = b4[c * 64 + lane]; }

    const float C2 = -13.287712379549449f / 1024.0f;   // -log2(10000)/D
    const float K2 = 0.9821718931198913f;              // 10000^(-1/512)
    const int   dl = lane << 2;
    const float fb0 = exp2f(C2 * (float)dl);
    const float SQD = 32.0f;

    __syncthreads();                                   // bookLDS ready

    #pragma unroll
    for (int r = 0; r < 2; ++r) {
        const int row = base + r;
        const float sf = (float)(row & (SEQ_ - 1));
        const float w  = r ? w1 : w0;
        const int  bt  = r ? bt1 : bt0;
        const float4* __restrict__ bkl = &bookLDS[bt * 256];

        float4 x[4];
        float sum = 0.0f, sq = 0.0f;
        float fb = fb0;
        #pragma unroll
        for (int c = 0; c < 4; ++c) {
            const float a0 = sf * fb;
            const float a1 = sf * (fb * K2);
            const float sn0 = __sinf(a0), cs0 = __cosf(a0);
            const float sn1 = __sinf(a1), cs1 = __cosf(a1);
            fb *= 0.1f;
            const float4 bk = bkl[c * 64 + lane];
            x[c].x = e[r][c].x * SQD + sn0 * w + bk.x;
            x[c].y = e[r][c].y * SQD + cs0 * w + bk.y;
            x[c].z = e[r][c].z * SQD + sn1 * w + bk.z;
            x[c].w = e[r][c].w * SQD + cs1 * w + bk.w;
            sum += (x[c].x + x[c].y) + (x[c].z + x[c].w);
            sq  += (x[c].x * x[c].x + x[c].y * x[c].y) + (x[c].z * x[c].z + x[c].w * x[c].w);
        }

        #pragma unroll
        for (int off = 32; off >= 1; off >>= 1) {
            sum += __shfl_xor(sum, off, 64);
            sq  += __shfl_xor(sq,  off, 64);
        }
        const float mean = sum * (1.0f / (float)DIM);
        const float var  = sq * (1.0f / (float)DIM) - mean * mean;
        const float rstd = rsqrtf(var + 1e-5f);

        float4* __restrict__ orow = reinterpret_cast<float4*>(out) + (size_t)row * 256;
        #pragma unroll
        for (int c = 0; c < 4; ++c) {
            float4 o;
            o.x = (x[c].x - mean) * rstd * g[c].x + b[c].x;
            o.y = (x[c].y - mean) * rstd * g[c].y + b[c].y;
            o.z = (x[c].z - mean) * rstd * g[c].z + b[c].z;
            o.w = (x[c].w - mean) * rstd * g[c].w + b[c].w;
            orow[c * 64 + lane] = o;
        }
    }
}

extern "C" void kernel_launch(void* const* d_in, const int* in_sizes, int n_in,
                              void* d_out, int out_size, void* d_ws, size_t ws_size,
                              hipStream_t stream) {
    const int*   token_ids  = (const int*)d_in[0];
    const int*   verse_pos  = (const int*)d_in[1];
    const int*   book_types = (const int*)d_in[2];
    const float* emb_table  = (const float*)d_in[3];
    const float* book_table = (const float*)d_in[4];
    const float* ln_gamma   = (const float*)d_in[5];
    const float* ln_beta    = (const float*)d_in[6];
    float* out = (float*)d_out;

    dim3 grid((NBAT * SEQ_) / 8);   // 4 waves/block * 2 rows/wave
    dim3 block(256);
    // DIAGNOSTIC: 8 identical idempotent dispatches. #1 cold, #2-8 L3-warm.
    for (int k = 0; k < 8; ++k) {
        verse_embed_ln_kernel<<<grid, block, 0, stream>>>(
            token_ids, verse_pos, book_types, emb_table, book_table,
            ln_gamma, ln_beta, out);
    }
}

// Round 7
// 14.924 us; speedup vs baseline: 6.5020x; 6.5020x over previous
//
#include <hip/hip_runtime.h>

#define DIM   1024
#define SEQ_  2048
#define NBAT  4

typedef float nativef4 __attribute__((ext_vector_type(4)));

// One 64-lane wave per row, 4 rows per 256-thread block. x[] in registers,
// in-wave shuffle reduction (no LDS/barrier). Output written with
// nontemporal stores: output is write-once per replay with no reuse, so
// keep it out of L2 and leave L2 capacity to the embedding-gather stream.
__global__ __launch_bounds__(256) void verse_embed_ln_kernel(
    const int*   __restrict__ token_ids,    // [B,S]
    const int*   __restrict__ verse_pos,    // [B,S]
    const int*   __restrict__ book_types,   // [B,S]
    const float* __restrict__ emb_table,    // [VOCAB,D]
    const float* __restrict__ book_table,   // [4,D]
    const float* __restrict__ gamma,        // [D]
    const float* __restrict__ beta,         // [D]
    float*       __restrict__ out)          // [B,S,D]
{
    const int wid  = threadIdx.x >> 6;
    const int lane = threadIdx.x & 63;
    const int row  = (blockIdx.x << 2) + wid;   // 0 .. B*S-1
    const int s    = row & (SEQ_ - 1);

    // wave-uniform per-row metadata (scalarized)
    const int tok   = token_ids[row];
    const int bt    = book_types[row];
    const int v     = verse_pos[row];
    const int vprev = (s == 0) ? -1 : verse_pos[row - 1];
    // verse_positions sorted per row (zeros first) => run-start test is local
    const float w = (v != 0 && v != vprev) ? 1.2f : 1.0f;

    const float4* __restrict__ erow = reinterpret_cast<const float4*>(emb_table)  + (size_t)tok * 256;
    const float4* __restrict__ brow = reinterpret_cast<const float4*>(book_table) + (size_t)bt  * 256;

    // issue all gathers up front (MLP against L2/L3 latency)
    float4 e[4], bk[4];
    #pragma unroll
    for (int c = 0; c < 4; ++c) e[c]  = erow[c * 64 + lane];
    #pragma unroll
    for (int c = 0; c < 4; ++c) bk[c] = brow[c * 64 + lane];

    // frequencies: f(d)=10000^(-d/1024); f(d+2)=f(d)*K2; f(d+256)=f(d)*0.1
    const float C2 = -13.287712379549449f / 1024.0f;   // -log2(10000)/D
    const float K2 = 0.9821718931198913f;              // 10000^(-1/512)
    const int   dl = lane << 2;
    const float sf = (float)s;
    float fb = exp2f(C2 * (float)dl);
    const float SQD = 32.0f;

    float4 x[4];
    float sum = 0.0f, sq = 0.0f;
    #pragma unroll
    for (int c = 0; c < 4; ++c) {
        const float a0 = sf * fb;
        const float a1 = sf * (fb * K2);
        const float sn0 = __sinf(a0), cs0 = __cosf(a0);
        const float sn1 = __sinf(a1), cs1 = __cosf(a1);
        fb *= 0.1f;
        x[c].x = e[c].x * SQD + sn0 * w + bk[c].x;
        x[c].y = e[c].y * SQD + cs0 * w + bk[c].y;
        x[c].z = e[c].z * SQD + sn1 * w + bk[c].z;
        x[c].w = e[c].w * SQD + cs1 * w + bk[c].w;
        sum += (x[c].x + x[c].y) + (x[c].z + x[c].w);
        sq  += (x[c].x * x[c].x + x[c].y * x[c].y) + (x[c].z * x[c].z + x[c].w * x[c].w);
    }

    #pragma unroll
    for (int off = 32; off >= 1; off >>= 1) {
        sum += __shfl_xor(sum, off, 64);
        sq  += __shfl_xor(sq,  off, 64);
    }

    const float mean = sum * (1.0f / (float)DIM);
    const float var  = sq * (1.0f / (float)DIM) - mean * mean;
    const float rstd = rsqrtf(var + 1e-5f);

    const float4* __restrict__ g4 = reinterpret_cast<const float4*>(gamma);
    const float4* __restrict__ b4 = reinterpret_cast<const float4*>(beta);
    nativef4* __restrict__ orow = reinterpret_cast<nativef4*>(out) + (size_t)row * 256;
    #pragma unroll
    for (int c = 0; c < 4; ++c) {
        const float4 g  = g4[c * 64 + lane];
        const float4 bb = b4[c * 64 + lane];
        nativef4 o;
        o.x = (x[c].x - mean) * rstd * g.x + bb.x;
        o.y = (x[c].y - mean) * rstd * g.y + bb.y;
        o.z = (x[c].z - mean) * rstd * g.z + bb.z;
        o.w = (x[c].w - mean) * rstd * g.w + bb.w;
        __builtin_nontemporal_store(o, &orow[c * 64 + lane]);
    }
}

extern "C" void kernel_launch(void* const* d_in, const int* in_sizes, int n_in,
                              void* d_out, int out_size, void* d_ws, size_t ws_size,
                              hipStream_t stream) {
    const int*   token_ids  = (const int*)d_in[0];
    const int*   verse_pos  = (const int*)d_in[1];
    const int*   book_types = (const int*)d_in[2];
    const float* emb_table  = (const float*)d_in[3];
    const float* book_table = (const float*)d_in[4];
    const float* ln_gamma   = (const float*)d_in[5];
    const float* ln_beta    = (const float*)d_in[6];
    float* out = (float*)d_out;

    dim3 grid((NBAT * SEQ_) / 4);   // one wave per row, 4 rows per 256-thread block
    dim3 block(256);
    verse_embed_ln_kernel<<<grid, block, 0, stream>>>(
        token_ids, verse_pos, book_types, emb_table, book_table,
        ln_gamma, ln_beta, out);
}